// Round 1
// baseline (1558.349 us; speedup 1.0000x reference)
//
#include <hip/hip_runtime.h>

#define N_NODES 100000
#define N_EDGES 1600000
#define DIM 128
#define ACT 512
#define NG 64

// ---------------- CSR build ----------------

__global__ void k_count(const int* __restrict__ dst, int* __restrict__ cnt) {
    int e = blockIdx.x * blockDim.x + threadIdx.x;
    if (e < N_EDGES) atomicAdd(&cnt[dst[e]], 1);
}

__global__ void k_dis(const int* __restrict__ cnt, float* __restrict__ dis) {
    int i = blockIdx.x * blockDim.x + threadIdx.x;
    if (i < N_NODES) dis[i] = rsqrtf((float)(cnt[i] + 1));
}

// single-block exclusive scan of cnt[0..N) -> rowptr[0..N], cursor copy
__global__ void k_scan(const int* __restrict__ cnt, int* __restrict__ rowptr,
                       int* __restrict__ cursor) {
    __shared__ int s[1024];
    int t = threadIdx.x;
    int running = 0;
    for (int base = 0; base < N_NODES; base += 1024) {
        int idx = base + t;
        int v = (idx < N_NODES) ? cnt[idx] : 0;
        s[t] = v;
        __syncthreads();
        for (int off = 1; off < 1024; off <<= 1) {
            int add = (t >= off) ? s[t - off] : 0;
            __syncthreads();
            s[t] += add;
            __syncthreads();
        }
        int excl = s[t] - v;
        if (idx < N_NODES) {
            rowptr[idx] = running + excl;
            cursor[idx] = running + excl;
        }
        int tot = s[1023];
        __syncthreads();
        running += tot;
    }
    if (t == 0) rowptr[N_NODES] = running;
}

__global__ void k_fill(const int* __restrict__ src, const int* __restrict__ dst,
                       int* __restrict__ cursor, int* __restrict__ csr) {
    int e = blockIdx.x * blockDim.x + threadIdx.x;
    if (e < N_EDGES) {
        int d = dst[e];
        int pos = atomicAdd(&cursor[d], 1);
        csr[pos] = src[e];
    }
}

// ---------------- layer kernels ----------------

// hs1[i,k] = (x[i,:3] @ W1[:,k]) * dis[i]
__global__ void k_h1(const float* __restrict__ x, const float* __restrict__ W1,
                     const float* __restrict__ dis, float* __restrict__ hs) {
    int id = blockIdx.x * blockDim.x + threadIdx.x;
    if (id >= N_NODES * DIM) return;
    int i = id >> 7, k = id & 127;
    float v = x[i * 3 + 0] * W1[k] + x[i * 3 + 1] * W1[DIM + k] + x[i * 3 + 2] * W1[2 * DIM + k];
    hs[id] = v * dis[i];
}

// out[i,k] = [relu]( dis[i] * (hs[i,k] + sum_{s in in(i)} hs[s,k]) + bias[k] )
template <bool RELU>
__global__ void k_prop(const float* __restrict__ hs, const int* __restrict__ rowptr,
                       const int* __restrict__ csr, const float* __restrict__ dis,
                       const float* __restrict__ bias, float* __restrict__ out) {
    int i = blockIdx.x;
    int k = threadIdx.x;
    int r0 = rowptr[i], r1 = rowptr[i + 1];
    float acc = hs[i * DIM + k];
    for (int j = r0; j < r1; ++j) {
        int s = csr[j];
        acc += hs[s * DIM + k];
    }
    float v = dis[i] * acc + bias[k];
    if (RELU) v = fmaxf(v, 0.f);
    out[i * DIM + k] = v;
}

// out[i,k] = (in[i,:] @ W[:,k]) * dis[i]   (128x128 W)
__global__ void k_gemm_scale(const float* __restrict__ in, const float* __restrict__ W,
                             const float* __restrict__ dis, float* __restrict__ out) {
    __shared__ float ht[16][DIM];
    int k = threadIdx.x;
    int i0 = blockIdx.x * 16;
    for (int r = 0; r < 16; ++r) ht[r][k] = in[(i0 + r) * DIM + k];
    __syncthreads();
    float acc[16];
#pragma unroll
    for (int r = 0; r < 16; ++r) acc[r] = 0.f;
    for (int kk = 0; kk < DIM; kk += 4) {
        float w0 = W[(kk + 0) * DIM + k];
        float w1 = W[(kk + 1) * DIM + k];
        float w2 = W[(kk + 2) * DIM + k];
        float w3 = W[(kk + 3) * DIM + k];
#pragma unroll
        for (int r = 0; r < 16; ++r) {
            const float4 hv = *(const float4*)&ht[r][kk];
            acc[r] = fmaf(hv.x, w0, fmaf(hv.y, w1, fmaf(hv.z, w2, fmaf(hv.w, w3, acc[r]))));
        }
    }
    for (int r = 0; r < 16; ++r) out[(i0 + r) * DIM + k] = acc[r] * dis[i0 + r];
}

// pooling: batch is sorted; run-length accumulate 64 nodes per block
__global__ void k_pool(const float* __restrict__ h, const int* __restrict__ batch,
                       float* __restrict__ pool) {
    int k = threadIdx.x;
    int i0 = blockIdx.x * 64;
    if (i0 >= N_NODES) return;
    float racc = 0.f;
    int curb = batch[i0];
    for (int r = 0; r < 64; ++r) {
        int i = i0 + r;
        if (i >= N_NODES) break;
        int b = batch[i];
        if (b != curb) {
            atomicAdd(&pool[curb * DIM + k], racc);
            racc = 0.f;
            curb = b;
        }
        racc += h[i * DIM + k];
    }
    atomicAdd(&pool[curb * DIM + k], racc);
}

__global__ void k_cnts(const int* __restrict__ batch, float* __restrict__ cnts) {
    int i = blockIdx.x * blockDim.x + threadIdx.x;
    if (i < N_NODES) atomicAdd(&cnts[batch[i]], 1.0f);
}

// q[g,a] = (pool[g,:] @ Wf[:,a]) / cnt[g] + bf[a]
__global__ void k_final(const float* __restrict__ pool, const float* __restrict__ cnts,
                        const float* __restrict__ Wf, const float* __restrict__ bf,
                        float* __restrict__ out) {
    int id = blockIdx.x * blockDim.x + threadIdx.x;
    if (id >= NG * ACT) return;
    int g = id >> 9, a = id & 511;
    float inv = 1.0f / fmaxf(cnts[g], 1.0f);
    float acc = 0.f;
#pragma unroll 4
    for (int c = 0; c < DIM; ++c) acc = fmaf(pool[g * DIM + c], Wf[c * ACT + a], acc);
    out[id] = acc * inv + bf[a];
}

// ---------------- launch ----------------

static inline size_t align256(size_t x) { return (x + 255) & ~(size_t)255; }

extern "C" void kernel_launch(void* const* d_in, const int* in_sizes, int n_in,
                              void* d_out, int out_size, void* d_ws, size_t ws_size,
                              hipStream_t stream) {
    const float* x  = (const float*)d_in[0];
    const int*   ei = (const int*)d_in[1];
    const int*   batch = (const int*)d_in[2];
    const float* W1 = (const float*)d_in[3];
    const float* b1 = (const float*)d_in[4];
    const float* W2 = (const float*)d_in[5];
    const float* b2 = (const float*)d_in[6];
    const float* Wf = (const float*)d_in[7];
    const float* bf = (const float*)d_in[8];
    float* out = (float*)d_out;

    const int* src = ei;
    const int* dst = ei + N_EDGES;

    char* ws = (char*)d_ws;
    size_t off = 0;
    float* dis    = (float*)(ws + off); off = align256(off + N_NODES * 4);
    int*   rowptr = (int*)(ws + off);   off = align256(off + (N_NODES + 1) * 4);
    int*   cursor = (int*)(ws + off);   off = align256(off + N_NODES * 4);
    int*   cnt    = (int*)(ws + off);   off = align256(off + N_NODES * 4);
    int*   csr    = (int*)(ws + off);   off = align256(off + N_EDGES * 4);
    float* bufA   = (float*)(ws + off); off = align256(off + (size_t)N_NODES * DIM * 4);
    float* bufB   = (float*)(ws + off); off = align256(off + (size_t)N_NODES * DIM * 4);
    float* pool   = (float*)(ws + off); off = align256(off + NG * DIM * 4);
    float* cnts   = (float*)(ws + off); off = align256(off + NG * 4);

    hipMemsetAsync(cnt, 0, N_NODES * 4, stream);
    hipMemsetAsync(pool, 0, NG * DIM * 4, stream);
    hipMemsetAsync(cnts, 0, NG * 4, stream);

    k_count<<<(N_EDGES + 255) / 256, 256, 0, stream>>>(dst, cnt);
    k_dis<<<(N_NODES + 255) / 256, 256, 0, stream>>>(cnt, dis);
    k_scan<<<1, 1024, 0, stream>>>(cnt, rowptr, cursor);
    k_fill<<<(N_EDGES + 255) / 256, 256, 0, stream>>>(src, dst, cursor, csr);

    k_h1<<<(N_NODES * DIM + 255) / 256, 256, 0, stream>>>(x, W1, dis, bufA);
    k_prop<true><<<N_NODES, DIM, 0, stream>>>(bufA, rowptr, csr, dis, b1, bufB);
    k_gemm_scale<<<N_NODES / 16, DIM, 0, stream>>>(bufB, W2, dis, bufA);
    k_prop<false><<<N_NODES, DIM, 0, stream>>>(bufA, rowptr, csr, dis, b2, bufB);

    k_pool<<<(N_NODES + 63) / 64, DIM, 0, stream>>>(bufB, batch, pool);
    k_cnts<<<(N_NODES + 255) / 256, 256, 0, stream>>>(batch, cnts);
    k_final<<<(NG * ACT + 255) / 256, 256, 0, stream>>>(pool, cnts, Wf, bf, out);
}

// Round 2
// 658.256 us; speedup vs baseline: 2.3674x; 2.3674x over previous
//
#include <hip/hip_runtime.h>

#define N_NODES 100000
#define N_EDGES 1600000
#define DIM 128
#define ACT 512
#define NG 64
#define SCAN_B 1024
#define SCAN_NB ((N_NODES + SCAN_B - 1) / SCAN_B)   // 98

// ---------------- CSR build ----------------

// count in-degree AND record each edge's slot within its destination row
__global__ void k_count(const int* __restrict__ dst, int* __restrict__ cnt,
                        int* __restrict__ epos) {
    int e = blockIdx.x * blockDim.x + threadIdx.x;
    if (e < N_EDGES) {
        int d = dst[e];
        epos[e] = atomicAdd(&cnt[d], 1);
    }
}

__global__ void k_dis(const int* __restrict__ cnt, float* __restrict__ dis) {
    int i = blockIdx.x * blockDim.x + threadIdx.x;
    if (i < N_NODES) dis[i] = rsqrtf((float)(cnt[i] + 1));
}

// phase 1: per-block exclusive scan into rowptr (local), block totals to partial
__global__ void k_scan1(const int* __restrict__ cnt, int* __restrict__ rowptr,
                        int* __restrict__ partial) {
    __shared__ int s[SCAN_B];
    int t = threadIdx.x;
    int idx = blockIdx.x * SCAN_B + t;
    int v = (idx < N_NODES) ? cnt[idx] : 0;
    s[t] = v;
    __syncthreads();
    for (int off = 1; off < SCAN_B; off <<= 1) {
        int add = (t >= off) ? s[t - off] : 0;
        __syncthreads();
        s[t] += add;
        __syncthreads();
    }
    if (idx < N_NODES) rowptr[idx] = s[t] - v;
    if (t == SCAN_B - 1) partial[blockIdx.x] = s[SCAN_B - 1];
}

// phase 2: scan the 98 block totals (single small block), write grand total
__global__ void k_scan2(int* __restrict__ partial, int* __restrict__ rowptr) {
    __shared__ int s[128];
    int t = threadIdx.x;
    int v = (t < SCAN_NB) ? partial[t] : 0;
    s[t] = v;
    __syncthreads();
    for (int off = 1; off < 128; off <<= 1) {
        int add = (t >= off) ? s[t - off] : 0;
        __syncthreads();
        s[t] += add;
        __syncthreads();
    }
    if (t < SCAN_NB) partial[t] = s[t] - v;
    if (t == 127) rowptr[N_NODES] = s[127];
}

// phase 3: add scanned block offsets
__global__ void k_scan3(int* __restrict__ rowptr, const int* __restrict__ partial) {
    int idx = blockIdx.x * SCAN_B + threadIdx.x;
    if (idx < N_NODES) rowptr[idx] += partial[blockIdx.x];
}

// atomic-free fill: position fully determined by rowptr + per-edge slot
__global__ void k_fill(const int* __restrict__ src, const int* __restrict__ dst,
                       const int* __restrict__ rowptr, const int* __restrict__ epos,
                       int* __restrict__ csr) {
    int e = blockIdx.x * blockDim.x + threadIdx.x;
    if (e < N_EDGES) {
        csr[rowptr[dst[e]] + epos[e]] = src[e];
    }
}

// ---------------- layer kernels ----------------

// hs1[i,k] = (x[i,:3] @ W1[:,k]) * dis[i]
__global__ void k_h1(const float* __restrict__ x, const float* __restrict__ W1,
                     const float* __restrict__ dis, float* __restrict__ hs) {
    int id = blockIdx.x * blockDim.x + threadIdx.x;
    if (id >= N_NODES * DIM) return;
    int i = id >> 7, k = id & 127;
    float v = x[i * 3 + 0] * W1[k] + x[i * 3 + 1] * W1[DIM + k] + x[i * 3 + 2] * W1[2 * DIM + k];
    hs[id] = v * dis[i];
}

// out[i,k] = [relu]( dis[i] * (hs[i,k] + sum_{s in in(i)} hs[s,k]) + bias[k] )
template <bool RELU>
__global__ void k_prop(const float* __restrict__ hs, const int* __restrict__ rowptr,
                       const int* __restrict__ csr, const float* __restrict__ dis,
                       const float* __restrict__ bias, float* __restrict__ out) {
    int i = blockIdx.x;
    int k = threadIdx.x;
    int r0 = rowptr[i], r1 = rowptr[i + 1];
    float acc = hs[i * DIM + k];
    for (int j = r0; j < r1; ++j) {
        int s = csr[j];
        acc += hs[s * DIM + k];
    }
    float v = dis[i] * acc + bias[k];
    if (RELU) v = fmaxf(v, 0.f);
    out[i * DIM + k] = v;
}

// out[i,k] = (in[i,:] @ W[:,k]) * dis[i]   (128x128 W)
__global__ void k_gemm_scale(const float* __restrict__ in, const float* __restrict__ W,
                             const float* __restrict__ dis, float* __restrict__ out) {
    __shared__ float ht[16][DIM];
    int k = threadIdx.x;
    int i0 = blockIdx.x * 16;
    for (int r = 0; r < 16; ++r) ht[r][k] = in[(i0 + r) * DIM + k];
    __syncthreads();
    float acc[16];
#pragma unroll
    for (int r = 0; r < 16; ++r) acc[r] = 0.f;
    for (int kk = 0; kk < DIM; kk += 4) {
        float w0 = W[(kk + 0) * DIM + k];
        float w1 = W[(kk + 1) * DIM + k];
        float w2 = W[(kk + 2) * DIM + k];
        float w3 = W[(kk + 3) * DIM + k];
#pragma unroll
        for (int r = 0; r < 16; ++r) {
            const float4 hv = *(const float4*)&ht[r][kk];
            acc[r] = fmaf(hv.x, w0, fmaf(hv.y, w1, fmaf(hv.z, w2, fmaf(hv.w, w3, acc[r]))));
        }
    }
    for (int r = 0; r < 16; ++r) out[(i0 + r) * DIM + k] = acc[r] * dis[i0 + r];
}

// pooling: batch is sorted; run-length accumulate 64 nodes per block
__global__ void k_pool(const float* __restrict__ h, const int* __restrict__ batch,
                       float* __restrict__ pool) {
    int k = threadIdx.x;
    int i0 = blockIdx.x * 64;
    if (i0 >= N_NODES) return;
    float racc = 0.f;
    int curb = batch[i0];
    for (int r = 0; r < 64; ++r) {
        int i = i0 + r;
        if (i >= N_NODES) break;
        int b = batch[i];
        if (b != curb) {
            atomicAdd(&pool[curb * DIM + k], racc);
            racc = 0.f;
            curb = b;
        }
        racc += h[i * DIM + k];
    }
    atomicAdd(&pool[curb * DIM + k], racc);
}

// per-graph node counts from sorted batch via binary search (no atomics)
__global__ void k_bounds(const int* __restrict__ batch, float* __restrict__ cnts) {
    __shared__ int start[NG + 1];
    int t = threadIdx.x;
    if (t <= NG) {
        int lo = 0, hi = N_NODES;
        while (lo < hi) {
            int mid = (lo + hi) >> 1;
            if (batch[mid] < t) lo = mid + 1; else hi = mid;
        }
        start[t] = lo;
    }
    __syncthreads();
    if (t < NG) cnts[t] = (float)(start[t + 1] - start[t]);
}

// q[g,a] = (pool[g,:] @ Wf[:,a]) / cnt[g] + bf[a]
__global__ void k_final(const float* __restrict__ pool, const float* __restrict__ cnts,
                        const float* __restrict__ Wf, const float* __restrict__ bf,
                        float* __restrict__ out) {
    int id = blockIdx.x * blockDim.x + threadIdx.x;
    if (id >= NG * ACT) return;
    int g = id >> 9, a = id & 511;
    float inv = 1.0f / fmaxf(cnts[g], 1.0f);
    float acc = 0.f;
#pragma unroll 4
    for (int c = 0; c < DIM; ++c) acc = fmaf(pool[g * DIM + c], Wf[c * ACT + a], acc);
    out[id] = acc * inv + bf[a];
}

// ---------------- launch ----------------

static inline size_t align256(size_t x) { return (x + 255) & ~(size_t)255; }

extern "C" void kernel_launch(void* const* d_in, const int* in_sizes, int n_in,
                              void* d_out, int out_size, void* d_ws, size_t ws_size,
                              hipStream_t stream) {
    const float* x  = (const float*)d_in[0];
    const int*   ei = (const int*)d_in[1];
    const int*   batch = (const int*)d_in[2];
    const float* W1 = (const float*)d_in[3];
    const float* b1 = (const float*)d_in[4];
    const float* W2 = (const float*)d_in[5];
    const float* b2 = (const float*)d_in[6];
    const float* Wf = (const float*)d_in[7];
    const float* bf = (const float*)d_in[8];
    float* out = (float*)d_out;

    const int* src = ei;
    const int* dst = ei + N_EDGES;

    char* ws = (char*)d_ws;
    size_t off = 0;
    float* dis     = (float*)(ws + off); off = align256(off + N_NODES * 4);
    int*   rowptr  = (int*)(ws + off);   off = align256(off + (N_NODES + 1) * 4);
    int*   cnt     = (int*)(ws + off);   off = align256(off + N_NODES * 4);
    int*   partial = (int*)(ws + off);   off = align256(off + SCAN_NB * 4);
    int*   epos    = (int*)(ws + off);   off = align256(off + N_EDGES * 4);
    int*   csr     = (int*)(ws + off);   off = align256(off + N_EDGES * 4);
    float* bufA    = (float*)(ws + off); off = align256(off + (size_t)N_NODES * DIM * 4);
    float* bufB    = (float*)(ws + off); off = align256(off + (size_t)N_NODES * DIM * 4);
    float* pool    = (float*)(ws + off); off = align256(off + NG * DIM * 4);
    float* cnts    = (float*)(ws + off); off = align256(off + NG * 4);

    hipMemsetAsync(cnt, 0, N_NODES * 4, stream);
    hipMemsetAsync(pool, 0, NG * DIM * 4, stream);

    k_count<<<(N_EDGES + 255) / 256, 256, 0, stream>>>(dst, cnt, epos);
    k_dis<<<(N_NODES + 255) / 256, 256, 0, stream>>>(cnt, dis);
    k_scan1<<<SCAN_NB, SCAN_B, 0, stream>>>(cnt, rowptr, partial);
    k_scan2<<<1, 128, 0, stream>>>(partial, rowptr);
    k_scan3<<<SCAN_NB, SCAN_B, 0, stream>>>(rowptr, partial);
    k_fill<<<(N_EDGES + 255) / 256, 256, 0, stream>>>(src, dst, rowptr, epos, csr);

    k_h1<<<(N_NODES * DIM + 255) / 256, 256, 0, stream>>>(x, W1, dis, bufA);
    k_prop<true><<<N_NODES, DIM, 0, stream>>>(bufA, rowptr, csr, dis, b1, bufB);
    k_gemm_scale<<<N_NODES / 16, DIM, 0, stream>>>(bufB, W2, dis, bufA);
    k_prop<false><<<N_NODES, DIM, 0, stream>>>(bufA, rowptr, csr, dis, b2, bufB);

    k_pool<<<(N_NODES + 63) / 64, DIM, 0, stream>>>(bufB, batch, pool);
    k_bounds<<<1, 128, 0, stream>>>(batch, cnts);
    k_final<<<(NG * ACT + 255) / 256, 256, 0, stream>>>(pool, cnts, Wf, bf, out);
}

// Round 3
// 545.365 us; speedup vs baseline: 2.8574x; 1.2070x over previous
//
#include <hip/hip_runtime.h>

#define N_NODES 100000
#define N_EDGES 1600000
#define DIM 128
#define ACT 512
#define NG 64
#define SCAN_B 1024
#define SCAN_NB ((N_NODES + SCAN_B - 1) / SCAN_B)   // 98

// ---------------- CSR build ----------------

// count in-degree AND record each edge's slot within its destination row
__global__ void k_count(const int* __restrict__ dst, int* __restrict__ cnt,
                        int* __restrict__ epos) {
    int e = blockIdx.x * blockDim.x + threadIdx.x;
    if (e < N_EDGES) {
        int d = dst[e];
        epos[e] = atomicAdd(&cnt[d], 1);
    }
}

// phase 1: per-block exclusive scan into rowptr (local), block totals to partial
// also emits dis[i] = rsqrt(indeg+1) on the way through
__global__ void k_scan1(const int* __restrict__ cnt, int* __restrict__ rowptr,
                        int* __restrict__ partial, float* __restrict__ dis) {
    __shared__ int s[SCAN_B];
    int t = threadIdx.x;
    int idx = blockIdx.x * SCAN_B + t;
    int v = (idx < N_NODES) ? cnt[idx] : 0;
    if (idx < N_NODES) dis[idx] = rsqrtf((float)(v + 1));
    s[t] = v;
    __syncthreads();
    for (int off = 1; off < SCAN_B; off <<= 1) {
        int add = (t >= off) ? s[t - off] : 0;
        __syncthreads();
        s[t] += add;
        __syncthreads();
    }
    if (idx < N_NODES) rowptr[idx] = s[t] - v;
    if (t == SCAN_B - 1) partial[blockIdx.x] = s[SCAN_B - 1];
}

// phase 2: scan the 98 block totals (single small block), write grand total
__global__ void k_scan2(int* __restrict__ partial, int* __restrict__ rowptr) {
    __shared__ int s[128];
    int t = threadIdx.x;
    int v = (t < SCAN_NB) ? partial[t] : 0;
    s[t] = v;
    __syncthreads();
    for (int off = 1; off < 128; off <<= 1) {
        int add = (t >= off) ? s[t - off] : 0;
        __syncthreads();
        s[t] += add;
        __syncthreads();
    }
    if (t < SCAN_NB) partial[t] = s[t] - v;
    if (t == 127) rowptr[N_NODES] = s[127];
}

// phase 3: add scanned block offsets
__global__ void k_scan3(int* __restrict__ rowptr, const int* __restrict__ partial) {
    int idx = blockIdx.x * SCAN_B + threadIdx.x;
    if (idx < N_NODES) rowptr[idx] += partial[blockIdx.x];
}

// atomic-free fill: position fully determined by rowptr + per-edge slot
__global__ void k_fill(const int* __restrict__ src, const int* __restrict__ dst,
                       const int* __restrict__ rowptr, const int* __restrict__ epos,
                       int* __restrict__ csr) {
    int e = blockIdx.x * blockDim.x + threadIdx.x;
    if (e < N_EDGES) {
        csr[rowptr[dst[e]] + epos[e]] = src[e];
    }
}

// ---------------- layer kernels ----------------

// hs1[i,k] = (x[i,:3] @ W1[:,k]) * dis[i]
__global__ void k_h1(const float* __restrict__ x, const float* __restrict__ W1,
                     const float* __restrict__ dis, float* __restrict__ hs) {
    int id = blockIdx.x * blockDim.x + threadIdx.x;
    if (id >= N_NODES * DIM) return;
    int i = id >> 7, k = id & 127;
    float v = x[i * 3 + 0] * W1[k] + x[i * 3 + 1] * W1[DIM + k] + x[i * 3 + 2] * W1[2 * DIM + k];
    hs[id] = v * dis[i];
}

// out[i,:] = [relu]( dis[i] * (hs[i,:] + sum_{s in in(i)} hs[s,:]) + bias )
// One 64-lane wave per node, float2 per lane; neighbor loop unrolled x8/x4
// so up to 8 independent 512B row-gathers are in flight per wave (MLP).
template <bool RELU>
__global__ void k_prop(const float* __restrict__ hs, const int* __restrict__ rowptr,
                       const int* __restrict__ csr, const float* __restrict__ dis,
                       const float* __restrict__ bias, float* __restrict__ out) {
    int node = blockIdx.x * 4 + (threadIdx.x >> 6);
    int lane = threadIdx.x & 63;
    const float2* __restrict__ hs2 = (const float2*)hs;
    int r0 = rowptr[node], r1 = rowptr[node + 1];
    float2 self = hs2[(size_t)node * 64 + lane];
    float ax = self.x, ay = self.y;
    int j = r0;
    for (; j + 8 <= r1; j += 8) {
        int s0 = csr[j + 0], s1 = csr[j + 1], s2 = csr[j + 2], s3 = csr[j + 3];
        int s4 = csr[j + 4], s5 = csr[j + 5], s6 = csr[j + 6], s7 = csr[j + 7];
        float2 v0 = hs2[(size_t)s0 * 64 + lane];
        float2 v1 = hs2[(size_t)s1 * 64 + lane];
        float2 v2 = hs2[(size_t)s2 * 64 + lane];
        float2 v3 = hs2[(size_t)s3 * 64 + lane];
        float2 v4 = hs2[(size_t)s4 * 64 + lane];
        float2 v5 = hs2[(size_t)s5 * 64 + lane];
        float2 v6 = hs2[(size_t)s6 * 64 + lane];
        float2 v7 = hs2[(size_t)s7 * 64 + lane];
        ax += ((v0.x + v1.x) + (v2.x + v3.x)) + ((v4.x + v5.x) + (v6.x + v7.x));
        ay += ((v0.y + v1.y) + (v2.y + v3.y)) + ((v4.y + v5.y) + (v6.y + v7.y));
    }
    for (; j + 4 <= r1; j += 4) {
        int s0 = csr[j + 0], s1 = csr[j + 1], s2 = csr[j + 2], s3 = csr[j + 3];
        float2 v0 = hs2[(size_t)s0 * 64 + lane];
        float2 v1 = hs2[(size_t)s1 * 64 + lane];
        float2 v2 = hs2[(size_t)s2 * 64 + lane];
        float2 v3 = hs2[(size_t)s3 * 64 + lane];
        ax += (v0.x + v1.x) + (v2.x + v3.x);
        ay += (v0.y + v1.y) + (v2.y + v3.y);
    }
    for (; j < r1; ++j) {
        int s = csr[j];
        float2 v = hs2[(size_t)s * 64 + lane];
        ax += v.x;
        ay += v.y;
    }
    float d = dis[node];
    float vx = d * ax + bias[lane * 2 + 0];
    float vy = d * ay + bias[lane * 2 + 1];
    if (RELU) { vx = fmaxf(vx, 0.f); vy = fmaxf(vy, 0.f); }
    float2 o;
    o.x = vx;
    o.y = vy;
    ((float2*)out)[(size_t)node * 64 + lane] = o;
}

// out[i,k] = (in[i,:] @ W[:,k]) * dis[i]   (128x128 W)
__global__ void k_gemm_scale(const float* __restrict__ in, const float* __restrict__ W,
                             const float* __restrict__ dis, float* __restrict__ out) {
    __shared__ float ht[16][DIM];
    int k = threadIdx.x;
    int i0 = blockIdx.x * 16;
    for (int r = 0; r < 16; ++r) ht[r][k] = in[(i0 + r) * DIM + k];
    __syncthreads();
    float acc[16];
#pragma unroll
    for (int r = 0; r < 16; ++r) acc[r] = 0.f;
    for (int kk = 0; kk < DIM; kk += 4) {
        float w0 = W[(kk + 0) * DIM + k];
        float w1 = W[(kk + 1) * DIM + k];
        float w2 = W[(kk + 2) * DIM + k];
        float w3 = W[(kk + 3) * DIM + k];
#pragma unroll
        for (int r = 0; r < 16; ++r) {
            const float4 hv = *(const float4*)&ht[r][kk];
            acc[r] = fmaf(hv.x, w0, fmaf(hv.y, w1, fmaf(hv.z, w2, fmaf(hv.w, w3, acc[r]))));
        }
    }
    for (int r = 0; r < 16; ++r) out[(i0 + r) * DIM + k] = acc[r] * dis[i0 + r];
}

// pooling: batch is sorted; run-length accumulate 64 nodes per block
__global__ void k_pool(const float* __restrict__ h, const int* __restrict__ batch,
                       float* __restrict__ pool) {
    int k = threadIdx.x;
    int i0 = blockIdx.x * 64;
    if (i0 >= N_NODES) return;
    float racc = 0.f;
    int curb = batch[i0];
    for (int r = 0; r < 64; ++r) {
        int i = i0 + r;
        if (i >= N_NODES) break;
        int b = batch[i];
        if (b != curb) {
            atomicAdd(&pool[curb * DIM + k], racc);
            racc = 0.f;
            curb = b;
        }
        racc += h[i * DIM + k];
    }
    atomicAdd(&pool[curb * DIM + k], racc);
}

// per-graph node counts from sorted batch via binary search (no atomics)
__global__ void k_bounds(const int* __restrict__ batch, float* __restrict__ cnts) {
    __shared__ int start[NG + 1];
    int t = threadIdx.x;
    if (t <= NG) {
        int lo = 0, hi = N_NODES;
        while (lo < hi) {
            int mid = (lo + hi) >> 1;
            if (batch[mid] < t) lo = mid + 1; else hi = mid;
        }
        start[t] = lo;
    }
    __syncthreads();
    if (t < NG) cnts[t] = (float)(start[t + 1] - start[t]);
}

// q[g,a] = (pool[g,:] @ Wf[:,a]) / cnt[g] + bf[a]
__global__ void k_final(const float* __restrict__ pool, const float* __restrict__ cnts,
                        const float* __restrict__ Wf, const float* __restrict__ bf,
                        float* __restrict__ out) {
    int id = blockIdx.x * blockDim.x + threadIdx.x;
    if (id >= NG * ACT) return;
    int g = id >> 9, a = id & 511;
    float inv = 1.0f / fmaxf(cnts[g], 1.0f);
    float acc = 0.f;
#pragma unroll 4
    for (int c = 0; c < DIM; ++c) acc = fmaf(pool[g * DIM + c], Wf[c * ACT + a], acc);
    out[id] = acc * inv + bf[a];
}

// ---------------- launch ----------------

static inline size_t align256(size_t x) { return (x + 255) & ~(size_t)255; }

extern "C" void kernel_launch(void* const* d_in, const int* in_sizes, int n_in,
                              void* d_out, int out_size, void* d_ws, size_t ws_size,
                              hipStream_t stream) {
    const float* x  = (const float*)d_in[0];
    const int*   ei = (const int*)d_in[1];
    const int*   batch = (const int*)d_in[2];
    const float* W1 = (const float*)d_in[3];
    const float* b1 = (const float*)d_in[4];
    const float* W2 = (const float*)d_in[5];
    const float* b2 = (const float*)d_in[6];
    const float* Wf = (const float*)d_in[7];
    const float* bf = (const float*)d_in[8];
    float* out = (float*)d_out;

    const int* src = ei;
    const int* dst = ei + N_EDGES;

    char* ws = (char*)d_ws;
    size_t off = 0;
    float* dis     = (float*)(ws + off); off = align256(off + N_NODES * 4);
    int*   rowptr  = (int*)(ws + off);   off = align256(off + (N_NODES + 1) * 4);
    int*   cnt     = (int*)(ws + off);   off = align256(off + N_NODES * 4);
    int*   partial = (int*)(ws + off);   off = align256(off + SCAN_NB * 4);
    int*   epos    = (int*)(ws + off);   off = align256(off + N_EDGES * 4);
    int*   csr     = (int*)(ws + off);   off = align256(off + N_EDGES * 4);
    float* bufA    = (float*)(ws + off); off = align256(off + (size_t)N_NODES * DIM * 4);
    float* bufB    = (float*)(ws + off); off = align256(off + (size_t)N_NODES * DIM * 4);
    float* pool    = (float*)(ws + off); off = align256(off + NG * DIM * 4);
    float* cnts    = (float*)(ws + off); off = align256(off + NG * 4);

    hipMemsetAsync(cnt, 0, N_NODES * 4, stream);
    hipMemsetAsync(pool, 0, NG * DIM * 4, stream);

    k_count<<<(N_EDGES + 255) / 256, 256, 0, stream>>>(dst, cnt, epos);
    k_scan1<<<SCAN_NB, SCAN_B, 0, stream>>>(cnt, rowptr, partial, dis);
    k_scan2<<<1, 128, 0, stream>>>(partial, rowptr);
    k_scan3<<<SCAN_NB, SCAN_B, 0, stream>>>(rowptr, partial);
    k_fill<<<(N_EDGES + 255) / 256, 256, 0, stream>>>(src, dst, rowptr, epos, csr);

    k_h1<<<(N_NODES * DIM + 255) / 256, 256, 0, stream>>>(x, W1, dis, bufA);
    k_prop<true><<<N_NODES / 4, 256, 0, stream>>>(bufA, rowptr, csr, dis, b1, bufB);
    k_gemm_scale<<<N_NODES / 16, DIM, 0, stream>>>(bufB, W2, dis, bufA);
    k_prop<false><<<N_NODES / 4, 256, 0, stream>>>(bufA, rowptr, csr, dis, b2, bufB);

    k_pool<<<(N_NODES + 63) / 64, DIM, 0, stream>>>(bufB, batch, pool);
    k_bounds<<<1, 128, 0, stream>>>(batch, cnts);
    k_final<<<(NG * ACT + 255) / 256, 256, 0, stream>>>(pool, cnts, Wf, bf, out);
}

// Round 4
// 441.412 us; speedup vs baseline: 3.5304x; 1.2355x over previous
//
#include <hip/hip_runtime.h>

#define N_NODES 100000
#define N_EDGES 1600000
#define DIM 128
#define ACT 512
#define NG 64
#define SCAN_B 1024
#define SCAN_NB ((N_NODES + SCAN_B - 1) / SCAN_B)   // 98

__device__ __forceinline__ float bf2f(unsigned int hi16_at_low) {
    union { unsigned int i; float f; } v;
    v.i = hi16_at_low;
    return v.f;
}
__device__ __forceinline__ unsigned short f2bf(float f) {
    union { float f; unsigned int i; } v;
    v.f = f;
    unsigned int i = v.i;
    i += 0x7fffu + ((i >> 16) & 1u);   // round-to-nearest-even
    return (unsigned short)(i >> 16);
}

// ---------------- CSR build ----------------

__global__ void k_count(const int* __restrict__ dst, int* __restrict__ cnt,
                        int* __restrict__ epos) {
    int e = blockIdx.x * blockDim.x + threadIdx.x;
    if (e < N_EDGES) {
        int d = dst[e];
        epos[e] = atomicAdd(&cnt[d], 1);
    }
}

__global__ void k_scan1(const int* __restrict__ cnt, int* __restrict__ rowptr,
                        int* __restrict__ partial, float* __restrict__ dis) {
    __shared__ int s[SCAN_B];
    int t = threadIdx.x;
    int idx = blockIdx.x * SCAN_B + t;
    int v = (idx < N_NODES) ? cnt[idx] : 0;
    if (idx < N_NODES) dis[idx] = rsqrtf((float)(v + 1));
    s[t] = v;
    __syncthreads();
    for (int off = 1; off < SCAN_B; off <<= 1) {
        int add = (t >= off) ? s[t - off] : 0;
        __syncthreads();
        s[t] += add;
        __syncthreads();
    }
    if (idx < N_NODES) rowptr[idx] = s[t] - v;
    if (t == SCAN_B - 1) partial[blockIdx.x] = s[SCAN_B - 1];
}

__global__ void k_scan2(int* __restrict__ partial, int* __restrict__ rowptr) {
    __shared__ int s[128];
    int t = threadIdx.x;
    int v = (t < SCAN_NB) ? partial[t] : 0;
    s[t] = v;
    __syncthreads();
    for (int off = 1; off < 128; off <<= 1) {
        int add = (t >= off) ? s[t - off] : 0;
        __syncthreads();
        s[t] += add;
        __syncthreads();
    }
    if (t < SCAN_NB) partial[t] = s[t] - v;
    if (t == 127) rowptr[N_NODES] = s[127];
}

__global__ void k_scan3(int* __restrict__ rowptr, const int* __restrict__ partial) {
    int idx = blockIdx.x * SCAN_B + threadIdx.x;
    if (idx < N_NODES) rowptr[idx] += partial[blockIdx.x];
}

__global__ void k_fill(const int* __restrict__ src, const int* __restrict__ dst,
                       const int* __restrict__ rowptr, const int* __restrict__ epos,
                       int* __restrict__ csr) {
    int e = blockIdx.x * blockDim.x + threadIdx.x;
    if (e < N_EDGES) {
        csr[rowptr[dst[e]] + epos[e]] = src[e];
    }
}

// ---------------- layer kernels ----------------

// Fused layer-1: for node i, out[i,:] = relu( dis[i] * sum_{s in in(i)+self} (x[s,:3]@W1)*dis[s] + b1 )
// Per neighbor only 16 B of wave-uniform data (x[s,0..2], dis[s]) is read; the
// 2 columns each lane owns are recomputed in-register. Output stored bf16.
__global__ void k_prop1(const float* __restrict__ x, const int* __restrict__ rowptr,
                        const int* __restrict__ csr, const float* __restrict__ dis,
                        const float* __restrict__ W1, const float* __restrict__ b1,
                        unsigned int* __restrict__ out) {
    int node = blockIdx.x * 4 + (threadIdx.x >> 6);
    int lane = threadIdx.x & 63;
    int k0 = lane * 2, k1 = k0 + 1;
    float wa0 = W1[k0], wa1 = W1[DIM + k0], wa2 = W1[2 * DIM + k0];
    float wb0 = W1[k1], wb1 = W1[DIM + k1], wb2 = W1[2 * DIM + k1];
    int r0 = rowptr[node], r1 = rowptr[node + 1];
    // self term
    float sx0 = x[node * 3 + 0], sx1 = x[node * 3 + 1], sx2 = x[node * 3 + 2];
    float sd = dis[node];
    float a0 = (sx0 * wa0 + sx1 * wa1 + sx2 * wa2) * sd;
    float a1 = (sx0 * wb0 + sx1 * wb1 + sx2 * wb2) * sd;
    int j = r0;
    for (; j + 4 <= r1; j += 4) {
        int s0 = csr[j + 0], s1 = csr[j + 1], s2 = csr[j + 2], s3 = csr[j + 3];
        float x00 = x[s0 * 3], x01 = x[s0 * 3 + 1], x02 = x[s0 * 3 + 2];
        float x10 = x[s1 * 3], x11 = x[s1 * 3 + 1], x12 = x[s1 * 3 + 2];
        float x20 = x[s2 * 3], x21 = x[s2 * 3 + 1], x22 = x[s2 * 3 + 2];
        float x30 = x[s3 * 3], x31 = x[s3 * 3 + 1], x32 = x[s3 * 3 + 2];
        float d0 = dis[s0], d1 = dis[s1], d2 = dis[s2], d3 = dis[s3];
        a0 += (x00 * wa0 + x01 * wa1 + x02 * wa2) * d0;
        a1 += (x00 * wb0 + x01 * wb1 + x02 * wb2) * d0;
        a0 += (x10 * wa0 + x11 * wa1 + x12 * wa2) * d1;
        a1 += (x10 * wb0 + x11 * wb1 + x12 * wb2) * d1;
        a0 += (x20 * wa0 + x21 * wa1 + x22 * wa2) * d2;
        a1 += (x20 * wb0 + x21 * wb1 + x22 * wb2) * d2;
        a0 += (x30 * wa0 + x31 * wa1 + x32 * wa2) * d3;
        a1 += (x30 * wb0 + x31 * wb1 + x32 * wb2) * d3;
    }
    for (; j < r1; ++j) {
        int s = csr[j];
        float x0 = x[s * 3], x1 = x[s * 3 + 1], x2 = x[s * 3 + 2];
        float d = dis[s];
        a0 += (x0 * wa0 + x1 * wa1 + x2 * wa2) * d;
        a1 += (x0 * wb0 + x1 * wb1 + x2 * wb2) * d;
    }
    float v0 = fmaxf(sd * a0 + b1[k0], 0.f);
    float v1 = fmaxf(sd * a1 + b1[k1], 0.f);
    out[(size_t)node * 64 + lane] = (unsigned int)f2bf(v0) | ((unsigned int)f2bf(v1) << 16);
}

// hs2[i,k] = (h1relu[i,:] @ W2[:,k]) * dis[i]; bf16 in, fp32 accumulate, bf16 out
__global__ void k_gemm_scale(const unsigned int* __restrict__ in, const float* __restrict__ W,
                             const float* __restrict__ dis, unsigned int* __restrict__ out) {
    __shared__ float ht[16][DIM];
    int k = threadIdx.x;
    int i0 = blockIdx.x * 16;
    for (int r = 0; r < 16; ++r) {
        unsigned int p = in[(size_t)(i0 + r) * 64 + (k >> 1)];
        ht[r][k] = (k & 1) ? bf2f(p & 0xffff0000u) : bf2f(p << 16);
    }
    __syncthreads();
    float acc[16];
#pragma unroll
    for (int r = 0; r < 16; ++r) acc[r] = 0.f;
    for (int kk = 0; kk < DIM; kk += 4) {
        float w0 = W[(kk + 0) * DIM + k];
        float w1 = W[(kk + 1) * DIM + k];
        float w2 = W[(kk + 2) * DIM + k];
        float w3 = W[(kk + 3) * DIM + k];
#pragma unroll
        for (int r = 0; r < 16; ++r) {
            const float4 hv = *(const float4*)&ht[r][kk];
            acc[r] = fmaf(hv.x, w0, fmaf(hv.y, w1, fmaf(hv.z, w2, fmaf(hv.w, w3, acc[r]))));
        }
    }
    __syncthreads();
    __shared__ unsigned short ob[16][DIM];
    for (int r = 0; r < 16; ++r) ob[r][k] = f2bf(acc[r] * dis[i0 + r]);
    __syncthreads();
    if (k < 64) {
        for (int r = 0; r < 16; ++r) {
            unsigned int p = (unsigned int)ob[r][k * 2] | ((unsigned int)ob[r][k * 2 + 1] << 16);
            out[(size_t)(i0 + r) * 64 + k] = p;
        }
    }
}

// layer-2 propagation: bf16 row gather (4 B/lane), fp32 accumulate, fp32 out
__global__ void k_prop2(const unsigned int* __restrict__ hs, const int* __restrict__ rowptr,
                        const int* __restrict__ csr, const float* __restrict__ dis,
                        const float* __restrict__ bias, float* __restrict__ out) {
    int node = blockIdx.x * 4 + (threadIdx.x >> 6);
    int lane = threadIdx.x & 63;
    int r0 = rowptr[node], r1 = rowptr[node + 1];
    unsigned int sp = hs[(size_t)node * 64 + lane];
    float ax = bf2f(sp << 16), ay = bf2f(sp & 0xffff0000u);
    int j = r0;
    for (; j + 8 <= r1; j += 8) {
        int s0 = csr[j + 0], s1 = csr[j + 1], s2 = csr[j + 2], s3 = csr[j + 3];
        int s4 = csr[j + 4], s5 = csr[j + 5], s6 = csr[j + 6], s7 = csr[j + 7];
        unsigned int p0 = hs[(size_t)s0 * 64 + lane];
        unsigned int p1 = hs[(size_t)s1 * 64 + lane];
        unsigned int p2 = hs[(size_t)s2 * 64 + lane];
        unsigned int p3 = hs[(size_t)s3 * 64 + lane];
        unsigned int p4 = hs[(size_t)s4 * 64 + lane];
        unsigned int p5 = hs[(size_t)s5 * 64 + lane];
        unsigned int p6 = hs[(size_t)s6 * 64 + lane];
        unsigned int p7 = hs[(size_t)s7 * 64 + lane];
        ax += ((bf2f(p0 << 16) + bf2f(p1 << 16)) + (bf2f(p2 << 16) + bf2f(p3 << 16)))
            + ((bf2f(p4 << 16) + bf2f(p5 << 16)) + (bf2f(p6 << 16) + bf2f(p7 << 16)));
        ay += ((bf2f(p0 & 0xffff0000u) + bf2f(p1 & 0xffff0000u)) + (bf2f(p2 & 0xffff0000u) + bf2f(p3 & 0xffff0000u)))
            + ((bf2f(p4 & 0xffff0000u) + bf2f(p5 & 0xffff0000u)) + (bf2f(p6 & 0xffff0000u) + bf2f(p7 & 0xffff0000u)));
    }
    for (; j < r1; ++j) {
        int s = csr[j];
        unsigned int p = hs[(size_t)s * 64 + lane];
        ax += bf2f(p << 16);
        ay += bf2f(p & 0xffff0000u);
    }
    float d = dis[node];
    float2 o;
    o.x = d * ax + bias[lane * 2 + 0];
    o.y = d * ay + bias[lane * 2 + 1];
    ((float2*)out)[(size_t)node * 64 + lane] = o;
}

// pooling: batch is sorted; run-length accumulate 64 nodes per block
__global__ void k_pool(const float* __restrict__ h, const int* __restrict__ batch,
                       float* __restrict__ pool) {
    int k = threadIdx.x;
    int i0 = blockIdx.x * 64;
    if (i0 >= N_NODES) return;
    float racc = 0.f;
    int curb = batch[i0];
    for (int r = 0; r < 64; ++r) {
        int i = i0 + r;
        if (i >= N_NODES) break;
        int b = batch[i];
        if (b != curb) {
            atomicAdd(&pool[curb * DIM + k], racc);
            racc = 0.f;
            curb = b;
        }
        racc += h[i * DIM + k];
    }
    atomicAdd(&pool[curb * DIM + k], racc);
}

__global__ void k_bounds(const int* __restrict__ batch, float* __restrict__ cnts) {
    __shared__ int start[NG + 1];
    int t = threadIdx.x;
    if (t <= NG) {
        int lo = 0, hi = N_NODES;
        while (lo < hi) {
            int mid = (lo + hi) >> 1;
            if (batch[mid] < t) lo = mid + 1; else hi = mid;
        }
        start[t] = lo;
    }
    __syncthreads();
    if (t < NG) cnts[t] = (float)(start[t + 1] - start[t]);
}

__global__ void k_final(const float* __restrict__ pool, const float* __restrict__ cnts,
                        const float* __restrict__ Wf, const float* __restrict__ bf,
                        float* __restrict__ out) {
    int id = blockIdx.x * blockDim.x + threadIdx.x;
    if (id >= NG * ACT) return;
    int g = id >> 9, a = id & 511;
    float inv = 1.0f / fmaxf(cnts[g], 1.0f);
    float acc = 0.f;
#pragma unroll 4
    for (int c = 0; c < DIM; ++c) acc = fmaf(pool[g * DIM + c], Wf[c * ACT + a], acc);
    out[id] = acc * inv + bf[a];
}

// ---------------- launch ----------------

static inline size_t align256(size_t x) { return (x + 255) & ~(size_t)255; }

extern "C" void kernel_launch(void* const* d_in, const int* in_sizes, int n_in,
                              void* d_out, int out_size, void* d_ws, size_t ws_size,
                              hipStream_t stream) {
    const float* x  = (const float*)d_in[0];
    const int*   ei = (const int*)d_in[1];
    const int*   batch = (const int*)d_in[2];
    const float* W1 = (const float*)d_in[3];
    const float* b1 = (const float*)d_in[4];
    const float* W2 = (const float*)d_in[5];
    const float* b2 = (const float*)d_in[6];
    const float* Wf = (const float*)d_in[7];
    const float* bf = (const float*)d_in[8];
    float* out = (float*)d_out;

    const int* src = ei;
    const int* dst = ei + N_EDGES;

    char* ws = (char*)d_ws;
    size_t off = 0;
    float* dis     = (float*)(ws + off); off = align256(off + N_NODES * 4);
    int*   rowptr  = (int*)(ws + off);   off = align256(off + (N_NODES + 1) * 4);
    int*   cnt     = (int*)(ws + off);   off = align256(off + N_NODES * 4);
    int*   partial = (int*)(ws + off);   off = align256(off + SCAN_NB * 4);
    int*   epos    = (int*)(ws + off);   off = align256(off + N_EDGES * 4);
    int*   csr     = (int*)(ws + off);   off = align256(off + N_EDGES * 4);
    unsigned int* h1b = (unsigned int*)(ws + off); off = align256(off + (size_t)N_NODES * 64 * 4);
    unsigned int* h2b = (unsigned int*)(ws + off); off = align256(off + (size_t)N_NODES * 64 * 4);
    float* out2    = (float*)(ws + off); off = align256(off + (size_t)N_NODES * DIM * 4);
    float* pool    = (float*)(ws + off); off = align256(off + NG * DIM * 4);
    float* cnts    = (float*)(ws + off); off = align256(off + NG * 4);

    hipMemsetAsync(cnt, 0, N_NODES * 4, stream);
    hipMemsetAsync(pool, 0, NG * DIM * 4, stream);

    k_count<<<(N_EDGES + 255) / 256, 256, 0, stream>>>(dst, cnt, epos);
    k_scan1<<<SCAN_NB, SCAN_B, 0, stream>>>(cnt, rowptr, partial, dis);
    k_scan2<<<1, 128, 0, stream>>>(partial, rowptr);
    k_scan3<<<SCAN_NB, SCAN_B, 0, stream>>>(rowptr, partial);
    k_fill<<<(N_EDGES + 255) / 256, 256, 0, stream>>>(src, dst, rowptr, epos, csr);

    k_prop1<<<N_NODES / 4, 256, 0, stream>>>(x, rowptr, csr, dis, W1, b1, h1b);
    k_gemm_scale<<<N_NODES / 16, DIM, 0, stream>>>(h1b, W2, dis, h2b);
    k_prop2<<<N_NODES / 4, 256, 0, stream>>>(h2b, rowptr, csr, dis, b2, out2);

    k_pool<<<(N_NODES + 63) / 64, DIM, 0, stream>>>(out2, batch, pool);
    k_bounds<<<1, 128, 0, stream>>>(batch, cnts);
    k_final<<<(NG * ACT + 255) / 256, 256, 0, stream>>>(pool, cnts, Wf, bf, out);
}

// Round 5
// 389.617 us; speedup vs baseline: 3.9997x; 1.1329x over previous
//
#include <hip/hip_runtime.h>

#define N_NODES 100000
#define N_EDGES 1600000
#define DIM 128
#define ACT 512
#define NG 64
#define SCAN_B 1024
#define SCAN_NB ((N_NODES + SCAN_B - 1) / SCAN_B)   // 98

__device__ __forceinline__ float bf2f(unsigned int hi16_at_low) {
    union { unsigned int i; float f; } v;
    v.i = hi16_at_low;
    return v.f;
}
__device__ __forceinline__ unsigned short f2bf(float f) {
    union { float f; unsigned int i; } v;
    v.f = f;
    unsigned int i = v.i;
    i += 0x7fffu + ((i >> 16) & 1u);   // round-to-nearest-even
    return (unsigned short)(i >> 16);
}

// ---------------- CSR build ----------------

__global__ void k_count(const int* __restrict__ dst, int* __restrict__ cnt,
                        int* __restrict__ epos) {
    int e = blockIdx.x * blockDim.x + threadIdx.x;
    if (e < N_EDGES) {
        int d = dst[e];
        epos[e] = atomicAdd(&cnt[d], 1);
    }
}

__global__ void k_scan1(const int* __restrict__ cnt, int* __restrict__ rowptr,
                        int* __restrict__ partial, float* __restrict__ dis) {
    __shared__ int s[SCAN_B];
    int t = threadIdx.x;
    int idx = blockIdx.x * SCAN_B + t;
    int v = (idx < N_NODES) ? cnt[idx] : 0;
    if (idx < N_NODES) dis[idx] = rsqrtf((float)(v + 1));
    s[t] = v;
    __syncthreads();
    for (int off = 1; off < SCAN_B; off <<= 1) {
        int add = (t >= off) ? s[t - off] : 0;
        __syncthreads();
        s[t] += add;
        __syncthreads();
    }
    if (idx < N_NODES) rowptr[idx] = s[t] - v;
    if (t == SCAN_B - 1) partial[blockIdx.x] = s[SCAN_B - 1];
}

__global__ void k_scan2(int* __restrict__ partial, int* __restrict__ rowptr) {
    __shared__ int s[128];
    int t = threadIdx.x;
    int v = (t < SCAN_NB) ? partial[t] : 0;
    s[t] = v;
    __syncthreads();
    for (int off = 1; off < 128; off <<= 1) {
        int add = (t >= off) ? s[t - off] : 0;
        __syncthreads();
        s[t] += add;
        __syncthreads();
    }
    if (t < SCAN_NB) partial[t] = s[t] - v;
    if (t == 127) rowptr[N_NODES] = s[127];
}

__global__ void k_scan3(int* __restrict__ rowptr, const int* __restrict__ partial) {
    int idx = blockIdx.x * SCAN_B + threadIdx.x;
    if (idx < N_NODES) rowptr[idx] += partial[blockIdx.x];
}

__global__ void k_fill(const int* __restrict__ src, const int* __restrict__ dst,
                       const int* __restrict__ rowptr, const int* __restrict__ epos,
                       int* __restrict__ csr) {
    int e = blockIdx.x * blockDim.x + threadIdx.x;
    if (e < N_EDGES) {
        csr[rowptr[dst[e]] + epos[e]] = src[e];
    }
}

// ---------------- layer 1: aggregate rank-3 inputs, then dense ----------------

// xd[i] = (x[i,0]*dis[i], x[i,1]*dis[i], x[i,2]*dis[i], dis[i])
__global__ void k_pack(const float* __restrict__ x, const float* __restrict__ dis,
                       float4* __restrict__ xd) {
    int i = blockIdx.x * blockDim.x + threadIdx.x;
    if (i >= N_NODES) return;
    float d = dis[i];
    float4 v;
    v.x = x[i * 3 + 0] * d;
    v.y = x[i * 3 + 1] * d;
    v.z = x[i * 3 + 2] * d;
    v.w = d;
    xd[i] = v;
}

// agg[i] = dis[i] * (xd[i].xyz + sum_{s in in(i)} xd[s].xyz)   (thread per node)
__global__ void k_agg1(const float4* __restrict__ xd, const int* __restrict__ rowptr,
                       const int* __restrict__ csr, float4* __restrict__ agg) {
    int i = blockIdx.x * blockDim.x + threadIdx.x;
    if (i >= N_NODES) return;
    int r0 = rowptr[i], r1 = rowptr[i + 1];
    float4 self = xd[i];
    float d = self.w;
    float a0 = self.x, a1 = self.y, a2 = self.z;
    int j = r0;
    for (; j + 4 <= r1; j += 4) {
        int s0 = csr[j + 0], s1 = csr[j + 1], s2 = csr[j + 2], s3 = csr[j + 3];
        float4 v0 = xd[s0];
        float4 v1 = xd[s1];
        float4 v2 = xd[s2];
        float4 v3 = xd[s3];
        a0 += (v0.x + v1.x) + (v2.x + v3.x);
        a1 += (v0.y + v1.y) + (v2.y + v3.y);
        a2 += (v0.z + v1.z) + (v2.z + v3.z);
    }
    for (; j < r1; ++j) {
        float4 v = xd[csr[j]];
        a0 += v.x;
        a1 += v.y;
        a2 += v.z;
    }
    float4 o;
    o.x = a0 * d;
    o.y = a1 * d;
    o.z = a2 * d;
    o.w = 0.f;
    agg[i] = o;
}

// h1[i,k] = relu(agg[i]@W1[:,k] + b1[k]), bf16-packed output
__global__ void k_dense1(const float4* __restrict__ agg, const float* __restrict__ W1,
                         const float* __restrict__ b1, unsigned int* __restrict__ out) {
    int id = blockIdx.x * blockDim.x + threadIdx.x;
    if (id >= N_NODES * 64) return;
    int i = id >> 6, kp = id & 63;
    int k0 = kp * 2, k1 = k0 + 1;
    float4 a = agg[i];
    float v0 = fmaf(a.x, W1[k0], fmaf(a.y, W1[DIM + k0], fmaf(a.z, W1[2 * DIM + k0], b1[k0])));
    float v1 = fmaf(a.x, W1[k1], fmaf(a.y, W1[DIM + k1], fmaf(a.z, W1[2 * DIM + k1], b1[k1])));
    v0 = fmaxf(v0, 0.f);
    v1 = fmaxf(v1, 0.f);
    out[id] = (unsigned int)f2bf(v0) | ((unsigned int)f2bf(v1) << 16);
}

// ---------------- layer 2 ----------------

// hs2[i,k] = (h1relu[i,:] @ W2[:,k]) * dis[i]; bf16 in, fp32 accumulate, bf16 out
__global__ void k_gemm_scale(const unsigned int* __restrict__ in, const float* __restrict__ W,
                             const float* __restrict__ dis, unsigned int* __restrict__ out) {
    __shared__ float ht[16][DIM];
    int k = threadIdx.x;
    int i0 = blockIdx.x * 16;
    for (int r = 0; r < 16; ++r) {
        unsigned int p = in[(size_t)(i0 + r) * 64 + (k >> 1)];
        ht[r][k] = (k & 1) ? bf2f(p & 0xffff0000u) : bf2f(p << 16);
    }
    __syncthreads();
    float acc[16];
#pragma unroll
    for (int r = 0; r < 16; ++r) acc[r] = 0.f;
    for (int kk = 0; kk < DIM; kk += 4) {
        float w0 = W[(kk + 0) * DIM + k];
        float w1 = W[(kk + 1) * DIM + k];
        float w2 = W[(kk + 2) * DIM + k];
        float w3 = W[(kk + 3) * DIM + k];
#pragma unroll
        for (int r = 0; r < 16; ++r) {
            const float4 hv = *(const float4*)&ht[r][kk];
            acc[r] = fmaf(hv.x, w0, fmaf(hv.y, w1, fmaf(hv.z, w2, fmaf(hv.w, w3, acc[r]))));
        }
    }
    __syncthreads();
    __shared__ unsigned short ob[16][DIM];
    for (int r = 0; r < 16; ++r) ob[r][k] = f2bf(acc[r] * dis[i0 + r]);
    __syncthreads();
    if (k < 64) {
        for (int r = 0; r < 16; ++r) {
            unsigned int p = (unsigned int)ob[r][k * 2] | ((unsigned int)ob[r][k * 2 + 1] << 16);
            out[(size_t)(i0 + r) * 64 + k] = p;
        }
    }
}

// layer-2 propagation: bf16 row gather (4 B/lane), fp32 accumulate, fp32 out
__global__ void k_prop2(const unsigned int* __restrict__ hs, const int* __restrict__ rowptr,
                        const int* __restrict__ csr, const float* __restrict__ dis,
                        const float* __restrict__ bias, float* __restrict__ out) {
    int node = blockIdx.x * 4 + (threadIdx.x >> 6);
    int lane = threadIdx.x & 63;
    int r0 = rowptr[node], r1 = rowptr[node + 1];
    unsigned int sp = hs[(size_t)node * 64 + lane];
    float ax = bf2f(sp << 16), ay = bf2f(sp & 0xffff0000u);
    int j = r0;
    for (; j + 8 <= r1; j += 8) {
        int s0 = csr[j + 0], s1 = csr[j + 1], s2 = csr[j + 2], s3 = csr[j + 3];
        int s4 = csr[j + 4], s5 = csr[j + 5], s6 = csr[j + 6], s7 = csr[j + 7];
        unsigned int p0 = hs[(size_t)s0 * 64 + lane];
        unsigned int p1 = hs[(size_t)s1 * 64 + lane];
        unsigned int p2 = hs[(size_t)s2 * 64 + lane];
        unsigned int p3 = hs[(size_t)s3 * 64 + lane];
        unsigned int p4 = hs[(size_t)s4 * 64 + lane];
        unsigned int p5 = hs[(size_t)s5 * 64 + lane];
        unsigned int p6 = hs[(size_t)s6 * 64 + lane];
        unsigned int p7 = hs[(size_t)s7 * 64 + lane];
        ax += ((bf2f(p0 << 16) + bf2f(p1 << 16)) + (bf2f(p2 << 16) + bf2f(p3 << 16)))
            + ((bf2f(p4 << 16) + bf2f(p5 << 16)) + (bf2f(p6 << 16) + bf2f(p7 << 16)));
        ay += ((bf2f(p0 & 0xffff0000u) + bf2f(p1 & 0xffff0000u)) + (bf2f(p2 & 0xffff0000u) + bf2f(p3 & 0xffff0000u)))
            + ((bf2f(p4 & 0xffff0000u) + bf2f(p5 & 0xffff0000u)) + (bf2f(p6 & 0xffff0000u) + bf2f(p7 & 0xffff0000u)));
    }
    for (; j < r1; ++j) {
        int s = csr[j];
        unsigned int p = hs[(size_t)s * 64 + lane];
        ax += bf2f(p << 16);
        ay += bf2f(p & 0xffff0000u);
    }
    float d = dis[node];
    float2 o;
    o.x = d * ax + bias[lane * 2 + 0];
    o.y = d * ay + bias[lane * 2 + 1];
    ((float2*)out)[(size_t)node * 64 + lane] = o;
}

// ---------------- pooling / head ----------------

__global__ void k_pool(const float* __restrict__ h, const int* __restrict__ batch,
                       float* __restrict__ pool) {
    int k = threadIdx.x;
    int i0 = blockIdx.x * 64;
    if (i0 >= N_NODES) return;
    float racc = 0.f;
    int curb = batch[i0];
    for (int r = 0; r < 64; ++r) {
        int i = i0 + r;
        if (i >= N_NODES) break;
        int b = batch[i];
        if (b != curb) {
            atomicAdd(&pool[curb * DIM + k], racc);
            racc = 0.f;
            curb = b;
        }
        racc += h[i * DIM + k];
    }
    atomicAdd(&pool[curb * DIM + k], racc);
}

__global__ void k_bounds(const int* __restrict__ batch, float* __restrict__ cnts) {
    __shared__ int start[NG + 1];
    int t = threadIdx.x;
    if (t <= NG) {
        int lo = 0, hi = N_NODES;
        while (lo < hi) {
            int mid = (lo + hi) >> 1;
            if (batch[mid] < t) lo = mid + 1; else hi = mid;
        }
        start[t] = lo;
    }
    __syncthreads();
    if (t < NG) cnts[t] = (float)(start[t + 1] - start[t]);
}

__global__ void k_final(const float* __restrict__ pool, const float* __restrict__ cnts,
                        const float* __restrict__ Wf, const float* __restrict__ bf,
                        float* __restrict__ out) {
    int id = blockIdx.x * blockDim.x + threadIdx.x;
    if (id >= NG * ACT) return;
    int g = id >> 9, a = id & 511;
    float inv = 1.0f / fmaxf(cnts[g], 1.0f);
    float acc = 0.f;
#pragma unroll 4
    for (int c = 0; c < DIM; ++c) acc = fmaf(pool[g * DIM + c], Wf[c * ACT + a], acc);
    out[id] = acc * inv + bf[a];
}

// ---------------- launch ----------------

static inline size_t align256(size_t x) { return (x + 255) & ~(size_t)255; }

extern "C" void kernel_launch(void* const* d_in, const int* in_sizes, int n_in,
                              void* d_out, int out_size, void* d_ws, size_t ws_size,
                              hipStream_t stream) {
    const float* x  = (const float*)d_in[0];
    const int*   ei = (const int*)d_in[1];
    const int*   batch = (const int*)d_in[2];
    const float* W1 = (const float*)d_in[3];
    const float* b1 = (const float*)d_in[4];
    const float* W2 = (const float*)d_in[5];
    const float* b2 = (const float*)d_in[6];
    const float* Wf = (const float*)d_in[7];
    const float* bf = (const float*)d_in[8];
    float* out = (float*)d_out;

    const int* src = ei;
    const int* dst = ei + N_EDGES;

    char* ws = (char*)d_ws;
    size_t off = 0;
    float* dis     = (float*)(ws + off); off = align256(off + N_NODES * 4);
    int*   rowptr  = (int*)(ws + off);   off = align256(off + (N_NODES + 1) * 4);
    int*   cnt     = (int*)(ws + off);   off = align256(off + N_NODES * 4);
    int*   partial = (int*)(ws + off);   off = align256(off + SCAN_NB * 4);
    int*   epos    = (int*)(ws + off);   off = align256(off + N_EDGES * 4);
    int*   csr     = (int*)(ws + off);   off = align256(off + N_EDGES * 4);
    float4* xd     = (float4*)(ws + off); off = align256(off + (size_t)N_NODES * 16);
    float4* agg    = (float4*)(ws + off); off = align256(off + (size_t)N_NODES * 16);
    unsigned int* h1b = (unsigned int*)(ws + off); off = align256(off + (size_t)N_NODES * 64 * 4);
    unsigned int* h2b = (unsigned int*)(ws + off); off = align256(off + (size_t)N_NODES * 64 * 4);
    float* out2    = (float*)(ws + off); off = align256(off + (size_t)N_NODES * DIM * 4);
    float* pool    = (float*)(ws + off); off = align256(off + NG * DIM * 4);
    float* cnts    = (float*)(ws + off); off = align256(off + NG * 4);

    hipMemsetAsync(cnt, 0, N_NODES * 4, stream);
    hipMemsetAsync(pool, 0, NG * DIM * 4, stream);

    k_count<<<(N_EDGES + 255) / 256, 256, 0, stream>>>(dst, cnt, epos);
    k_scan1<<<SCAN_NB, SCAN_B, 0, stream>>>(cnt, rowptr, partial, dis);
    k_scan2<<<1, 128, 0, stream>>>(partial, rowptr);
    k_scan3<<<SCAN_NB, SCAN_B, 0, stream>>>(rowptr, partial);
    k_fill<<<(N_EDGES + 255) / 256, 256, 0, stream>>>(src, dst, rowptr, epos, csr);

    k_pack<<<(N_NODES + 255) / 256, 256, 0, stream>>>(x, dis, xd);
    k_agg1<<<(N_NODES + 255) / 256, 256, 0, stream>>>(xd, rowptr, csr, agg);
    k_dense1<<<(N_NODES * 64 + 255) / 256, 256, 0, stream>>>(agg, W1, b1, h1b);
    k_gemm_scale<<<N_NODES / 16, DIM, 0, stream>>>(h1b, W2, dis, h2b);
    k_prop2<<<N_NODES / 4, 256, 0, stream>>>(h2b, rowptr, csr, dis, b2, out2);

    k_pool<<<(N_NODES + 63) / 64, DIM, 0, stream>>>(out2, batch, pool);
    k_bounds<<<1, 128, 0, stream>>>(batch, cnts);
    k_final<<<(NG * ACT + 255) / 256, 256, 0, stream>>>(pool, cnts, Wf, bf, out);
}

// Round 6
// 332.275 us; speedup vs baseline: 4.6899x; 1.1726x over previous
//
#include <hip/hip_runtime.h>

#define N_NODES 100000
#define N_EDGES 1600000
#define DIM 128
#define ACT 512
#define NG 64
#define SCAN_B 1024
#define SCAN_NB ((N_NODES + SCAN_B - 1) / SCAN_B)   // 98

typedef __attribute__((ext_vector_type(8))) short bf16x8;
typedef __attribute__((ext_vector_type(4))) float f32x4;

__device__ __forceinline__ float bf2f(unsigned int hi16_at_low) {
    union { unsigned int i; float f; } v;
    v.i = hi16_at_low;
    return v.f;
}
__device__ __forceinline__ unsigned short f2bf(float f) {
    union { float f; unsigned int i; } v;
    v.f = f;
    unsigned int i = v.i;
    i += 0x7fffu + ((i >> 16) & 1u);   // round-to-nearest-even
    return (unsigned short)(i >> 16);
}

// ---------------- CSR build ----------------

__global__ void k_count(const int* __restrict__ dst, int* __restrict__ cnt,
                        int* __restrict__ epos) {
    int e = blockIdx.x * blockDim.x + threadIdx.x;
    if (e < N_EDGES) {
        int d = dst[e];
        epos[e] = atomicAdd(&cnt[d], 1);
    }
}

// scan phase 1 + dis + xd pack fused
__global__ void k_scan1(const int* __restrict__ cnt, int* __restrict__ rowptr,
                        int* __restrict__ partial, float* __restrict__ dis,
                        const float* __restrict__ x, float4* __restrict__ xd) {
    __shared__ int s[SCAN_B];
    int t = threadIdx.x;
    int idx = blockIdx.x * SCAN_B + t;
    int v = (idx < N_NODES) ? cnt[idx] : 0;
    if (idx < N_NODES) {
        float d = rsqrtf((float)(v + 1));
        dis[idx] = d;
        float4 p;
        p.x = x[idx * 3 + 0] * d;
        p.y = x[idx * 3 + 1] * d;
        p.z = x[idx * 3 + 2] * d;
        p.w = d;
        xd[idx] = p;
    }
    s[t] = v;
    __syncthreads();
    for (int off = 1; off < SCAN_B; off <<= 1) {
        int add = (t >= off) ? s[t - off] : 0;
        __syncthreads();
        s[t] += add;
        __syncthreads();
    }
    if (idx < N_NODES) rowptr[idx] = s[t] - v;
    if (t == SCAN_B - 1) partial[blockIdx.x] = s[SCAN_B - 1];
}

__global__ void k_scan2(int* __restrict__ partial, int* __restrict__ rowptr) {
    __shared__ int s[128];
    int t = threadIdx.x;
    int v = (t < SCAN_NB) ? partial[t] : 0;
    s[t] = v;
    __syncthreads();
    for (int off = 1; off < 128; off <<= 1) {
        int add = (t >= off) ? s[t - off] : 0;
        __syncthreads();
        s[t] += add;
        __syncthreads();
    }
    if (t < SCAN_NB) partial[t] = s[t] - v;
    if (t == 127) rowptr[N_NODES] = s[127];
}

__global__ void k_scan3(int* __restrict__ rowptr, const int* __restrict__ partial) {
    int idx = blockIdx.x * SCAN_B + threadIdx.x;
    if (idx < N_NODES) rowptr[idx] += partial[blockIdx.x];
}

__global__ void k_fill(const int* __restrict__ src, const int* __restrict__ dst,
                       const int* __restrict__ rowptr, const int* __restrict__ epos,
                       int* __restrict__ csr) {
    int e = blockIdx.x * blockDim.x + threadIdx.x;
    if (e < N_EDGES) {
        csr[rowptr[dst[e]] + epos[e]] = src[e];
    }
}

// ---------------- layer 1 aggregation (rank-3) ----------------

// agg[i] = dis[i] * (xd[i].xyz + sum_{s in in(i)} xd[s].xyz)
__global__ void k_agg1(const float4* __restrict__ xd, const int* __restrict__ rowptr,
                       const int* __restrict__ csr, float4* __restrict__ agg) {
    int i = blockIdx.x * blockDim.x + threadIdx.x;
    if (i >= N_NODES) return;
    int r0 = rowptr[i], r1 = rowptr[i + 1];
    float4 self = xd[i];
    float d = self.w;
    float a0 = self.x, a1 = self.y, a2 = self.z;
    int j = r0;
    for (; j + 4 <= r1; j += 4) {
        int s0 = csr[j + 0], s1 = csr[j + 1], s2 = csr[j + 2], s3 = csr[j + 3];
        float4 v0 = xd[s0];
        float4 v1 = xd[s1];
        float4 v2 = xd[s2];
        float4 v3 = xd[s3];
        a0 += (v0.x + v1.x) + (v2.x + v3.x);
        a1 += (v0.y + v1.y) + (v2.y + v3.y);
        a2 += (v0.z + v1.z) + (v2.z + v3.z);
    }
    for (; j < r1; ++j) {
        float4 v = xd[csr[j]];
        a0 += v.x;
        a1 += v.y;
        a2 += v.z;
    }
    float4 o;
    o.x = a0 * d;
    o.y = a1 * d;
    o.z = a2 * d;
    o.w = 0.f;
    agg[i] = o;
}

// ---------------- W2 -> bf16 fragment-swizzled ----------------
// W2s[((k>>3)*128 + n)*8 + (k&7)] = bf16(W2[k][n]); lane (quad q) in K-step s
// reads its 8 k-elements for column n as one contiguous 16B load.
__global__ void k_w2cvt(const float* __restrict__ W2, unsigned short* __restrict__ W2s) {
    int tid = blockIdx.x * blockDim.x + threadIdx.x;
    if (tid >= DIM * DIM) return;
    int k = tid >> 7, n = tid & 127;
    W2s[(size_t)(k >> 3) * 1024 + n * 8 + (k & 7)] = f2bf(W2[tid]);
}

// ---------------- fused h1 (rank-3 dense + relu) -> MFMA @W2 -> *dis -> bf16 ----------------
// Block = 256 thr = 4 waves; tile 64 nodes x 128 dims. Wave w owns n-range [32w,32w+32).
// A-fragment (h1 in bf16) is recomputed per lane from agg (3 FMA/elem) — never materialized.
__global__ __launch_bounds__(256) void k_h1h2(const float4* __restrict__ agg,
                                              const float* __restrict__ W1,
                                              const float* __restrict__ b1,
                                              const unsigned short* __restrict__ W2s,
                                              const float* __restrict__ dis,
                                              unsigned short* __restrict__ h2b) {
    int wave = threadIdx.x >> 6;
    int lane = threadIdx.x & 63;
    int q = lane >> 4;
    int n15 = lane & 15;
    int i0 = blockIdx.x * 64;
    int nb = wave * 32;

    // cache the A-rows (agg) each lane needs: row m = lane&15 of each 16-row M-tile
    float4 ag[4];
#pragma unroll
    for (int t = 0; t < 4; ++t) {
        int node = i0 + t * 16 + n15;
        ag[t] = agg[node < N_NODES ? node : (N_NODES - 1)];
    }

    f32x4 acc[4][2];
#pragma unroll
    for (int t = 0; t < 4; ++t)
        for (int h = 0; h < 2; ++h)
            acc[t][h] = (f32x4){0.f, 0.f, 0.f, 0.f};

    const uint4* bp = (const uint4*)W2s;

#pragma unroll
    for (int s = 0; s < 4; ++s) {
        int kd = s * 32 + q * 8;
        // W1 columns kd..kd+7 (3 input rows) + bias
        float4 wr0a = *(const float4*)&W1[0 * DIM + kd];
        float4 wr0b = *(const float4*)&W1[0 * DIM + kd + 4];
        float4 wr1a = *(const float4*)&W1[1 * DIM + kd];
        float4 wr1b = *(const float4*)&W1[1 * DIM + kd + 4];
        float4 wr2a = *(const float4*)&W1[2 * DIM + kd];
        float4 wr2b = *(const float4*)&W1[2 * DIM + kd + 4];
        float4 bba  = *(const float4*)&b1[kd];
        float4 bbb  = *(const float4*)&b1[kd + 4];
        float w0[8] = {wr0a.x, wr0a.y, wr0a.z, wr0a.w, wr0b.x, wr0b.y, wr0b.z, wr0b.w};
        float w1[8] = {wr1a.x, wr1a.y, wr1a.z, wr1a.w, wr1b.x, wr1b.y, wr1b.z, wr1b.w};
        float w2[8] = {wr2a.x, wr2a.y, wr2a.z, wr2a.w, wr2b.x, wr2b.y, wr2b.z, wr2b.w};
        float bb[8] = {bba.x, bba.y, bba.z, bba.w, bbb.x, bbb.y, bbb.z, bbb.w};

        // B fragments for this wave's two 16-col tiles
        int brow = (s * 4 + q) * 128;
        union { uint4 r; bf16x8 v; } B0, B1;
        B0.r = bp[brow + nb + n15];
        B1.r = bp[brow + nb + 16 + n15];

#pragma unroll
        for (int t = 0; t < 4; ++t) {
            union { bf16x8 v; unsigned short u[8]; } A;
            float4 a = ag[t];
#pragma unroll
            for (int j = 0; j < 8; ++j) {
                float h = fmaf(a.x, w0[j], fmaf(a.y, w1[j], fmaf(a.z, w2[j], bb[j])));
                A.u[j] = f2bf(fmaxf(h, 0.f));
            }
            acc[t][0] = __builtin_amdgcn_mfma_f32_16x16x32_bf16(A.v, B0.v, acc[t][0], 0, 0, 0);
            acc[t][1] = __builtin_amdgcn_mfma_f32_16x16x32_bf16(A.v, B1.v, acc[t][1], 0, 0, 0);
        }
    }

    // epilogue: D row = quad*4 + reg, col = lane&15; scale by dis[row], store bf16
#pragma unroll
    for (int t = 0; t < 4; ++t) {
#pragma unroll
        for (int h = 0; h < 2; ++h) {
            int col = nb + h * 16 + n15;
#pragma unroll
            for (int r = 0; r < 4; ++r) {
                int row = i0 + t * 16 + q * 4 + r;
                if (row < N_NODES)
                    h2b[(size_t)row * DIM + col] = f2bf(acc[t][h][r] * dis[row]);
            }
        }
    }
}

// ---------------- layer-2 propagation: bf16 gather, fp32 acc, bf16 out ----------------

__global__ void k_prop2(const unsigned int* __restrict__ hs, const int* __restrict__ rowptr,
                        const int* __restrict__ csr, const float* __restrict__ dis,
                        const float* __restrict__ bias, unsigned int* __restrict__ out) {
    int node = blockIdx.x * 4 + (threadIdx.x >> 6);
    int lane = threadIdx.x & 63;
    int r0 = rowptr[node], r1 = rowptr[node + 1];
    unsigned int sp = hs[(size_t)node * 64 + lane];
    float ax = bf2f(sp << 16), ay = bf2f(sp & 0xffff0000u);
    int j = r0;
    for (; j + 8 <= r1; j += 8) {
        int s0 = csr[j + 0], s1 = csr[j + 1], s2 = csr[j + 2], s3 = csr[j + 3];
        int s4 = csr[j + 4], s5 = csr[j + 5], s6 = csr[j + 6], s7 = csr[j + 7];
        unsigned int p0 = hs[(size_t)s0 * 64 + lane];
        unsigned int p1 = hs[(size_t)s1 * 64 + lane];
        unsigned int p2 = hs[(size_t)s2 * 64 + lane];
        unsigned int p3 = hs[(size_t)s3 * 64 + lane];
        unsigned int p4 = hs[(size_t)s4 * 64 + lane];
        unsigned int p5 = hs[(size_t)s5 * 64 + lane];
        unsigned int p6 = hs[(size_t)s6 * 64 + lane];
        unsigned int p7 = hs[(size_t)s7 * 64 + lane];
        ax += ((bf2f(p0 << 16) + bf2f(p1 << 16)) + (bf2f(p2 << 16) + bf2f(p3 << 16)))
            + ((bf2f(p4 << 16) + bf2f(p5 << 16)) + (bf2f(p6 << 16) + bf2f(p7 << 16)));
        ay += ((bf2f(p0 & 0xffff0000u) + bf2f(p1 & 0xffff0000u)) + (bf2f(p2 & 0xffff0000u) + bf2f(p3 & 0xffff0000u)))
            + ((bf2f(p4 & 0xffff0000u) + bf2f(p5 & 0xffff0000u)) + (bf2f(p6 & 0xffff0000u) + bf2f(p7 & 0xffff0000u)));
    }
    for (; j < r1; ++j) {
        int s = csr[j];
        unsigned int p = hs[(size_t)s * 64 + lane];
        ax += bf2f(p << 16);
        ay += bf2f(p & 0xffff0000u);
    }
    float d = dis[node];
    float vx = d * ax + bias[lane * 2 + 0];
    float vy = d * ay + bias[lane * 2 + 1];
    out[(size_t)node * 64 + lane] = (unsigned int)f2bf(vx) | ((unsigned int)f2bf(vy) << 16);
}

// ---------------- pooling / head ----------------

// batch sorted; one wave per 64 nodes, each thread owns a bf16 column pair
__global__ void k_pool(const unsigned int* __restrict__ h, const int* __restrict__ batch,
                       float* __restrict__ pool) {
    int t = threadIdx.x;   // 0..63
    int i0 = blockIdx.x * 64;
    if (i0 >= N_NODES) return;
    float rx = 0.f, ry = 0.f;
    int curb = batch[i0];
    for (int r = 0; r < 64; ++r) {
        int i = i0 + r;
        if (i >= N_NODES) break;
        int b = batch[i];
        if (b != curb) {
            atomicAdd(&pool[curb * DIM + t * 2 + 0], rx);
            atomicAdd(&pool[curb * DIM + t * 2 + 1], ry);
            rx = 0.f;
            ry = 0.f;
            curb = b;
        }
        unsigned int p = h[(size_t)i * 64 + t];
        rx += bf2f(p << 16);
        ry += bf2f(p & 0xffff0000u);
    }
    atomicAdd(&pool[curb * DIM + t * 2 + 0], rx);
    atomicAdd(&pool[curb * DIM + t * 2 + 1], ry);
}

__global__ void k_bounds(const int* __restrict__ batch, float* __restrict__ cnts) {
    __shared__ int start[NG + 1];
    int t = threadIdx.x;
    if (t <= NG) {
        int lo = 0, hi = N_NODES;
        while (lo < hi) {
            int mid = (lo + hi) >> 1;
            if (batch[mid] < t) lo = mid + 1; else hi = mid;
        }
        start[t] = lo;
    }
    __syncthreads();
    if (t < NG) cnts[t] = (float)(start[t + 1] - start[t]);
}

__global__ void k_final(const float* __restrict__ pool, const float* __restrict__ cnts,
                        const float* __restrict__ Wf, const float* __restrict__ bf,
                        float* __restrict__ out) {
    int id = blockIdx.x * blockDim.x + threadIdx.x;
    if (id >= NG * ACT) return;
    int g = id >> 9, a = id & 511;
    float inv = 1.0f / fmaxf(cnts[g], 1.0f);
    float acc = 0.f;
#pragma unroll 4
    for (int c = 0; c < DIM; ++c) acc = fmaf(pool[g * DIM + c], Wf[c * ACT + a], acc);
    out[id] = acc * inv + bf[a];
}

// ---------------- launch ----------------

static inline size_t align256(size_t x) { return (x + 255) & ~(size_t)255; }

extern "C" void kernel_launch(void* const* d_in, const int* in_sizes, int n_in,
                              void* d_out, int out_size, void* d_ws, size_t ws_size,
                              hipStream_t stream) {
    const float* x  = (const float*)d_in[0];
    const int*   ei = (const int*)d_in[1];
    const int*   batch = (const int*)d_in[2];
    const float* W1 = (const float*)d_in[3];
    const float* b1 = (const float*)d_in[4];
    const float* W2 = (const float*)d_in[5];
    const float* b2 = (const float*)d_in[6];
    const float* Wf = (const float*)d_in[7];
    const float* bf = (const float*)d_in[8];
    float* out = (float*)d_out;

    const int* src = ei;
    const int* dst = ei + N_EDGES;

    char* ws = (char*)d_ws;
    size_t off = 0;
    float* dis     = (float*)(ws + off); off = align256(off + N_NODES * 4);
    int*   rowptr  = (int*)(ws + off);   off = align256(off + (N_NODES + 1) * 4);
    int*   cnt     = (int*)(ws + off);   off = align256(off + N_NODES * 4);
    int*   partial = (int*)(ws + off);   off = align256(off + SCAN_NB * 4);
    int*   epos    = (int*)(ws + off);   off = align256(off + N_EDGES * 4);
    int*   csr     = (int*)(ws + off);   off = align256(off + N_EDGES * 4);
    float4* xd     = (float4*)(ws + off); off = align256(off + (size_t)N_NODES * 16);
    float4* agg    = (float4*)(ws + off); off = align256(off + (size_t)N_NODES * 16);
    unsigned short* W2s = (unsigned short*)(ws + off); off = align256(off + (size_t)DIM * DIM * 2);
    unsigned short* h2b = (unsigned short*)(ws + off); off = align256(off + (size_t)N_NODES * DIM * 2);
    unsigned int* out2b = (unsigned int*)(ws + off);   off = align256(off + (size_t)N_NODES * 64 * 4);
    float* pool    = (float*)(ws + off); off = align256(off + NG * DIM * 4);
    float* cnts    = (float*)(ws + off); off = align256(off + NG * 4);

    hipMemsetAsync(cnt, 0, N_NODES * 4, stream);
    hipMemsetAsync(pool, 0, NG * DIM * 4, stream);

    k_count<<<(N_EDGES + 255) / 256, 256, 0, stream>>>(dst, cnt, epos);
    k_w2cvt<<<(DIM * DIM + 255) / 256, 256, 0, stream>>>(W2, W2s);
    k_scan1<<<SCAN_NB, SCAN_B, 0, stream>>>(cnt, rowptr, partial, dis, x, xd);
    k_scan2<<<1, 128, 0, stream>>>(partial, rowptr);
    k_scan3<<<SCAN_NB, SCAN_B, 0, stream>>>(rowptr, partial);
    k_fill<<<(N_EDGES + 255) / 256, 256, 0, stream>>>(src, dst, rowptr, epos, csr);

    k_agg1<<<(N_NODES + 255) / 256, 256, 0, stream>>>(xd, rowptr, csr, agg);
    k_h1h2<<<(N_NODES + 63) / 64, 256, 0, stream>>>(agg, W1, b1, W2s, dis, h2b);
    k_prop2<<<N_NODES / 4, 256, 0, stream>>>((const unsigned int*)h2b, rowptr, csr, dis, b2, out2b);

    k_pool<<<(N_NODES + 63) / 64, 64, 0, stream>>>(out2b, batch, pool);
    k_bounds<<<1, 128, 0, stream>>>(batch, cnts);
    k_final<<<(NG * ACT + 255) / 256, 256, 0, stream>>>(pool, cnts, Wf, bf, out);
}